// Round 1
// 1503.757 us; speedup vs baseline: 1.4804x; 1.4804x over previous
//
#include <hip/hip_runtime.h>
#include <cstddef>

#define N_NODES 16384
#define N_FEAT  16384
#define EMBED   64
#define BATCH   4096
#define N_EDGES 524288

typedef __attribute__((ext_vector_type(8))) short bf16x8;  // 8 bf16 = 4 VGPR (MFMA A/B frag)
typedef __attribute__((ext_vector_type(4))) float f32x4;   // MFMA C/D frag

// fp32 -> bf16 round-to-nearest-even (bit trick, sign-safe)
__device__ __forceinline__ ushort f32_to_bf16(float f) {
    unsigned u = __float_as_uint(f);
    return (ushort)((u + 0x7FFFu + ((u >> 16) & 1u)) >> 16);
}
__device__ __forceinline__ float bf16_to_f32(ushort h) {
    return __uint_as_float((unsigned)h << 16);
}

// ---------------------------------------------------------------------------
// degree / dinv (deg buffer doubles as dinv after k_dinv)
__global__ void k_deg_init(float* __restrict__ deg) {
    int n = blockIdx.x * blockDim.x + threadIdx.x;
    if (n < N_NODES) deg[n] = 1.0f;            // self-loop
}
__global__ void k_deg_acc(const int* __restrict__ ei, float* __restrict__ deg) {
    int e = blockIdx.x * blockDim.x + threadIdx.x;
    if (e < N_EDGES) atomicAdd(&deg[ei[N_EDGES + e]], 1.0f);
}
__global__ void k_dinv(float* __restrict__ deg) {
    int n = blockIdx.x * blockDim.x + threadIdx.x;
    if (n < N_NODES) deg[n] = rsqrtf(deg[n]);
}

// ---------------------------------------------------------------------------
// CSR build: exclusive prefix scan of in-edge counts (deg-1), 1 block.
__global__ __launch_bounds__(1024) void k_scan(const float* __restrict__ deg,
                                               int* __restrict__ off,
                                               int* __restrict__ cur) {
    __shared__ int part[1024];
    const int t = threadIdx.x;
    int c[16];
    int s = 0;
    #pragma unroll
    for (int i = 0; i < 16; ++i) {
        c[i] = (int)deg[t * 16 + i] - 1;       // in-edges only (self-loop excluded)
        s += c[i];
    }
    part[t] = s;
    __syncthreads();
    for (int d = 1; d < 1024; d <<= 1) {       // Hillis-Steele inclusive scan
        int v = (t >= d) ? part[t - d] : 0;
        __syncthreads();
        part[t] += v;
        __syncthreads();
    }
    int run = (t == 0) ? 0 : part[t - 1];      // exclusive
    #pragma unroll
    for (int i = 0; i < 16; ++i) {
        off[t * 16 + i] = run;
        cur[t * 16 + i] = run;
        run += c[i];
    }
    if (t == 1023) off[N_NODES] = run;         // == N_EDGES
}

// bucket edges by dst: srcs[off[d] .. off[d+1]) = list of sources into d
__global__ void k_scatter(const int* __restrict__ ei, int* __restrict__ cur,
                          int* __restrict__ srcs) {
    int e = blockIdx.x * blockDim.x + threadIdx.x;
    if (e < N_EDGES) {
        int s = ei[e];
        int d = ei[N_EDGES + e];
        srcs[atomicAdd(&cur[d], 1)] = s;
    }
}

// ---------------------------------------------------------------------------
// Pack W (fp32 [16384][64]) into MFMA B-fragment order, split into hi/lo bf16.
// Frag f = (split*512 + kstep)*4 + coltile; lane l holds 8 bf16 at
// k = kstep*32 + (l>>4)*8 + j, n = coltile*16 + (l&15). 4 MB total, L2-hot.
__global__ void k_wpack(const float* __restrict__ W, short* __restrict__ Wpk) {
    int tid = blockIdx.x * blockDim.x + threadIdx.x;   // 262144
    int lane = tid & 63;
    int f = tid >> 6;                                  // 0..4095
    int ct = f & 3;
    int ks = (f >> 2) & 511;
    int sp = f >> 11;                                  // 0 = hi, 1 = lo
    int n = ct * 16 + (lane & 15);
    int kbase = ks * 32 + (lane >> 4) * 8;
    bf16x8 r;
    #pragma unroll
    for (int j = 0; j < 8; ++j) {
        float w = W[(size_t)(kbase + j) * EMBED + n];
        ushort h = f32_to_bf16(w);
        r[j] = (sp == 0) ? (short)h : (short)f32_to_bf16(w - bf16_to_f32(h));
    }
    *(bf16x8*)(Wpk + (size_t)f * 512 + lane * 8) = r;
}

__global__ void k_zero(float4* __restrict__ p) {
    p[blockIdx.x * blockDim.x + threadIdx.x] = make_float4(0.f, 0.f, 0.f, 0.f);
}

// ---------------------------------------------------------------------------
// xw = X @ W via bf16 split-2 MFMA (terms hh + hl + lh; ~2^-17 rel trunc).
// Block: 256 thr = 4 waves; tile 128 rows x 64 cols; K split 4-ways across
// blocks (grid 512 = 2 blocks/CU, 8 waves/CU) with atomicAdd epilogue.
// Wave w owns rows [w*32, w*32+32): 2 row-frags x 4 col-frags, 24 MFMA/kstep.
// LDS: X tile as hi/lo bf16, row stride 40 ushorts (80 B): 16B-aligned frag
// reads, bank pattern 20*r%32 -> 8 banks x 2-way (free per m136).
#define GBM 128
#define KSPLIT 4
#define KCHUNK (N_FEAT / KSPLIT)

__global__ __launch_bounds__(256, 2) void k_gemm(const float* __restrict__ X,
                                                 const short* __restrict__ Wpk,
                                                 float* __restrict__ xw) {
    __shared__ ushort Xh[GBM][40];
    __shared__ ushort Xl[GBM][40];

    const int t = threadIdx.x;
    const int rb = blockIdx.x & 127;                 // row block
    const int ks0 = (blockIdx.x >> 7) * (KCHUNK / 32);
    const int block_row = rb * GBM;
    const int w = t >> 6;
    const int lane = t & 63;
    const int g = lane >> 4;
    const int lr = lane & 15;
    const int srow = t >> 3;                         // staging: 8 thr/row
    const int sq = t & 7;                            // quad (4 floats) in row

    f32x4 acc[2][4] = {};

    for (int kt = 0; kt < KCHUNK / 32; ++kt) {
        const int kstep = ks0 + kt;
        const int k0 = kstep * 32;

        // B frags direct from packed global (L2-hot) — issue early
        bf16x8 bh[4], bl[4];
        #pragma unroll
        for (int ct = 0; ct < 4; ++ct) {
            const short* p = Wpk + (size_t)(kstep * 4 + ct) * 512 + lane * 8;
            bh[ct] = *(const bf16x8*)p;
            bl[ct] = *(const bf16x8*)(p + 1048576);  // +2048 frags = lo split
        }

        // stage X tile: coalesced float4 loads (8 rows x 128 B per inst)
        float4 v[4];
        #pragma unroll
        for (int i = 0; i < 4; ++i)
            v[i] = *(const float4*)(X + (size_t)(block_row + srow + i * 32) * N_FEAT + k0 + sq * 4);

        #pragma unroll
        for (int i = 0; i < 4; ++i) {
            float vv[4] = {v[i].x, v[i].y, v[i].z, v[i].w};
            ushort4 hv, lv;
            ushort* hp = (ushort*)&hv;
            ushort* lp = (ushort*)&lv;
            #pragma unroll
            for (int e = 0; e < 4; ++e) {
                ushort h = f32_to_bf16(vv[e]);
                hp[e] = h;
                lp[e] = f32_to_bf16(vv[e] - bf16_to_f32(h));  // exact residual, then RTN
            }
            int row = srow + i * 32;
            *(ushort4*)(&Xh[row][sq * 4]) = hv;
            *(ushort4*)(&Xl[row][sq * 4]) = lv;
        }
        __syncthreads();

        // A frags: lane l -> row (l&15), k-group (l>>4)*8, contiguous b128
        bf16x8 ah[2], al[2];
        #pragma unroll
        for (int rt = 0; rt < 2; ++rt) {
            int row = w * 32 + rt * 16 + lr;
            ah[rt] = *(const bf16x8*)(&Xh[row][g * 8]);
            al[rt] = *(const bf16x8*)(&Xl[row][g * 8]);
        }
        #pragma unroll
        for (int rt = 0; rt < 2; ++rt) {
            #pragma unroll
            for (int ct = 0; ct < 4; ++ct) {
                acc[rt][ct] = __builtin_amdgcn_mfma_f32_16x16x32_bf16(ah[rt], bh[ct], acc[rt][ct], 0, 0, 0);
                acc[rt][ct] = __builtin_amdgcn_mfma_f32_16x16x32_bf16(ah[rt], bl[ct], acc[rt][ct], 0, 0, 0);
                acc[rt][ct] = __builtin_amdgcn_mfma_f32_16x16x32_bf16(al[rt], bh[ct], acc[rt][ct], 0, 0, 0);
            }
        }
        __syncthreads();
    }

    // epilogue: C/D layout col = lane&15, row = (lane>>4)*4 + reg (m89-verified)
    #pragma unroll
    for (int rt = 0; rt < 2; ++rt)
        #pragma unroll
        for (int ct = 0; ct < 4; ++ct)
            #pragma unroll
            for (int r = 0; r < 4; ++r) {
                int row = block_row + w * 32 + rt * 16 + g * 4 + r;
                atomicAdd(&xw[(size_t)row * EMBED + ct * 16 + lr], acc[rt][ct][r]);
            }
}

// ---------------------------------------------------------------------------
// agg[n] = dinv[n] * ( dinv[n]*xw[n] + sum_{s in CSR[n]} dinv[s]*xw[s] )
// One wave per dst node; register accumulation, no atomics.
__global__ void k_gather(const int* __restrict__ off, const int* __restrict__ srcs,
                         const float* __restrict__ xw, const float* __restrict__ dinv,
                         float* __restrict__ agg) {
    int n = blockIdx.x * 4 + (threadIdx.x >> 6);
    int lane = threadIdx.x & 63;
    float dn = dinv[n];
    float acc = xw[(size_t)n * EMBED + lane] * dn;   // self-loop (x dn at end -> dn^2)
    int i = off[n], i1 = off[n + 1];
    for (; i + 1 < i1; i += 2) {                     // 2-way unroll: parallel loads
        int s0 = srcs[i], s1 = srcs[i + 1];
        float a0 = xw[(size_t)s0 * EMBED + lane] * dinv[s0];
        float a1 = xw[(size_t)s1 * EMBED + lane] * dinv[s1];
        acc += a0 + a1;
    }
    if (i < i1) {
        int s = srcs[i];
        acc += xw[(size_t)s * EMBED + lane] * dinv[s];
    }
    agg[(size_t)n * EMBED + lane] = acc * dn;
}

// ---------------------------------------------------------------------------
// out[b] = w_lin[i0] + w_lin[i1] + b_lin + dot(emb[i0]+b_gcn, emb[i1]+b_gcn)
__global__ void k_final(const int* __restrict__ x, const float* __restrict__ agg,
                        const float* __restrict__ b_gcn, const float* __restrict__ w_lin,
                        const float* __restrict__ b_lin, float* __restrict__ out) {
    int b = blockIdx.x * (blockDim.x >> 6) + (threadIdx.x >> 6);
    int lane = threadIdx.x & 63;
    if (b >= BATCH) return;
    int i0 = x[2 * b + 0];
    int i1 = x[2 * b + 1];
    float bg = b_gcn[lane];
    float e0 = agg[(size_t)i0 * EMBED + lane] + bg;
    float e1 = agg[(size_t)i1 * EMBED + lane] + bg;
    float p = e0 * e1;
    #pragma unroll
    for (int off = 32; off > 0; off >>= 1) p += __shfl_down(p, off, 64);
    if (lane == 0) out[b] = p + w_lin[i0] + w_lin[i1] + b_lin[0];
}

// ---------------------------------------------------------------------------
extern "C" void kernel_launch(void* const* d_in, const int* in_sizes, int n_in,
                              void* d_out, int out_size, void* d_ws, size_t ws_size,
                              hipStream_t stream) {
    (void)in_sizes; (void)n_in; (void)out_size; (void)ws_size;

    const int*   x   = (const int*)d_in[0];    // [BATCH, 2]
    const float* X   = (const float*)d_in[1];  // [N_NODES, N_FEAT]
    const int*   ei  = (const int*)d_in[2];    // [2, N_EDGES]
    const float* W   = (const float*)d_in[3];  // [N_FEAT, EMBED]
    const float* bg  = (const float*)d_in[4];  // [EMBED]
    const float* wl  = (const float*)d_in[5];  // [N_NODES]
    const float* bl  = (const float*)d_in[6];  // [1]
    float* out = (float*)d_out;                // [BATCH]

    // workspace layout (10.5 MB):
    //   0      : xw   4 MB
    //   4 MB   : agg  4 MB   (aliases Wpk: Wpk dead before k_gather writes agg)
    //   8 MB   : dinv 64 KB
    //   +128 KB: off  64 KB+4
    //   +256 KB: cur  64 KB
    //   +512 KB: srcs 2 MB
    char* ws = (char*)d_ws;
    float* xw   = (float*)(ws);
    float* agg  = (float*)(ws + (size_t)(4 << 20));
    short* Wpk  = (short*)(ws + (size_t)(4 << 20));
    float* dinv = (float*)(ws + (size_t)(8 << 20));
    int*   off  = (int*)  (ws + (size_t)(8 << 20) + (1 << 17));
    int*   cur  = (int*)  (ws + (size_t)(8 << 20) + (1 << 18));
    int*   srcs = (int*)  (ws + (size_t)(8 << 20) + (1 << 19));

    k_deg_init<<<N_NODES / 256, 256, 0, stream>>>(dinv);
    k_deg_acc<<<N_EDGES / 256, 256, 0, stream>>>(ei, dinv);
    k_scan<<<1, 1024, 0, stream>>>(dinv, off, cur);       // needs raw deg
    k_dinv<<<N_NODES / 256, 256, 0, stream>>>(dinv);      // deg -> rsqrt(deg)
    k_scatter<<<N_EDGES / 256, 256, 0, stream>>>(ei, cur, srcs);

    k_wpack<<<1024, 256, 0, stream>>>(W, Wpk);
    k_zero<<<1024, 256, 0, stream>>>((float4*)xw);
    k_gemm<<<(N_NODES / GBM) * KSPLIT, 256, 0, stream>>>(X, Wpk, xw);

    k_gather<<<N_NODES / 4, 256, 0, stream>>>(off, srcs, xw, dinv, agg);
    k_final<<<BATCH / 4, 256, 0, stream>>>(x, agg, bg, wl, bl, out);
}

// Round 2
// 1500.553 us; speedup vs baseline: 1.4835x; 1.0021x over previous
//
#include <hip/hip_runtime.h>
#include <cstddef>

#define N_NODES 16384
#define N_FEAT  16384
#define EMBED   64
#define BATCH   4096
#define N_EDGES 524288

typedef __attribute__((ext_vector_type(8))) short bf16x8;  // 8 bf16 = 4 VGPR (MFMA A/B frag)
typedef __attribute__((ext_vector_type(4))) float f32x4;   // MFMA C/D frag

// fp32 -> bf16 round-to-nearest-even (bit trick, sign-safe)
__device__ __forceinline__ ushort f32_to_bf16(float f) {
    unsigned u = __float_as_uint(f);
    return (ushort)((u + 0x7FFFu + ((u >> 16) & 1u)) >> 16);
}
__device__ __forceinline__ float bf16_to_f32(ushort h) {
    return __uint_as_float((unsigned)h << 16);
}

// split 8 fp32 (two float4) into hi/lo bf16x8 fragments
__device__ __forceinline__ void split8(float4 a, float4 b, bf16x8& h, bf16x8& l) {
    float f[8] = {a.x, a.y, a.z, a.w, b.x, b.y, b.z, b.w};
    #pragma unroll
    for (int j = 0; j < 8; ++j) {
        ushort hh = f32_to_bf16(f[j]);
        h[j] = (short)hh;
        l[j] = (short)f32_to_bf16(f[j] - bf16_to_f32(hh));
    }
}

// ---------------------------------------------------------------------------
// degree / dinv (deg buffer doubles as dinv after k_dinv)
__global__ void k_deg_init(float* __restrict__ deg) {
    int n = blockIdx.x * blockDim.x + threadIdx.x;
    if (n < N_NODES) deg[n] = 1.0f;            // self-loop
}
__global__ void k_deg_acc(const int* __restrict__ ei, float* __restrict__ deg) {
    int e = blockIdx.x * blockDim.x + threadIdx.x;
    if (e < N_EDGES) atomicAdd(&deg[ei[N_EDGES + e]], 1.0f);
}
__global__ void k_dinv(float* __restrict__ deg) {
    int n = blockIdx.x * blockDim.x + threadIdx.x;
    if (n < N_NODES) deg[n] = rsqrtf(deg[n]);
}

// ---------------------------------------------------------------------------
// CSR build: exclusive prefix scan of in-edge counts (deg-1), 1 block.
__global__ __launch_bounds__(1024) void k_scan(const float* __restrict__ deg,
                                               int* __restrict__ off,
                                               int* __restrict__ cur) {
    __shared__ int part[1024];
    const int t = threadIdx.x;
    int c[16];
    int s = 0;
    #pragma unroll
    for (int i = 0; i < 16; ++i) {
        c[i] = (int)deg[t * 16 + i] - 1;       // in-edges only (self-loop excluded)
        s += c[i];
    }
    part[t] = s;
    __syncthreads();
    for (int d = 1; d < 1024; d <<= 1) {       // Hillis-Steele inclusive scan
        int v = (t >= d) ? part[t - d] : 0;
        __syncthreads();
        part[t] += v;
        __syncthreads();
    }
    int run = (t == 0) ? 0 : part[t - 1];      // exclusive
    #pragma unroll
    for (int i = 0; i < 16; ++i) {
        off[t * 16 + i] = run;
        cur[t * 16 + i] = run;
        run += c[i];
    }
    if (t == 1023) off[N_NODES] = run;         // == N_EDGES
}

// bucket edges by dst: srcs[off[d] .. off[d+1]) = list of sources into d
__global__ void k_scatter(const int* __restrict__ ei, int* __restrict__ cur,
                          int* __restrict__ srcs) {
    int e = blockIdx.x * blockDim.x + threadIdx.x;
    if (e < N_EDGES) {
        int s = ei[e];
        int d = ei[N_EDGES + e];
        srcs[atomicAdd(&cur[d], 1)] = s;
    }
}

// ---------------------------------------------------------------------------
// Pack W (fp32 [16384][64]) into MFMA B-fragment order, split into hi/lo bf16.
// Frag f = (split*2048 + kstep*4 + coltile); lane l holds 8 bf16 at
// k = kstep*32 + (l>>4)*8 + j, n = coltile*16 + (l&15). 4 MB total, L2-hot.
__global__ void k_wpack(const float* __restrict__ W, short* __restrict__ Wpk) {
    int tid = blockIdx.x * blockDim.x + threadIdx.x;   // 262144
    int lane = tid & 63;
    int f = tid >> 6;                                  // 0..4095
    int ct = f & 3;
    int ks = (f >> 2) & 511;
    int sp = f >> 11;                                  // 0 = hi, 1 = lo
    int n = ct * 16 + (lane & 15);
    int kbase = ks * 32 + (lane >> 4) * 8;
    bf16x8 r;
    #pragma unroll
    for (int j = 0; j < 8; ++j) {
        float w = W[(size_t)(kbase + j) * EMBED + n];
        ushort h = f32_to_bf16(w);
        r[j] = (sp == 0) ? (short)h : (short)f32_to_bf16(w - bf16_to_f32(h));
    }
    *(bf16x8*)(Wpk + (size_t)f * 512 + lane * 8) = r;
}

// ---------------------------------------------------------------------------
// xw_part[kpl] = X[:, kslice] @ W[kslice, :] via bf16 split-2 MFMA
// (terms hh + hl + lh; ~2^-17 rel trunc).
// Grid 1024 = 128 row-blocks x KSPLIT=8 -> 4 blocks/CU, 16 waves/CU.
// Per block: 128x64 tile, 64 K-steps of BK=32; double-buffered LDS staged by
// global_load_lds (16B, raw fp32, zero staging VALU). XOR-swizzle granule
// (q ^= row&7) on SOURCE addr + READ addr (involution) -> conflict-free
// ds_read_b128 (8-clk floor). One barrier per K-step; stage(next) overlaps
// compute(cur) (T3-minimum 2-phase). Epilogue: plain stores (no atomics).
#define GBM 128
#define KSPLIT 8
#define KCHUNK (N_FEAT / KSPLIT)   // 2048
#define NSTEP (KCHUNK / 32)        // 64

__global__ __launch_bounds__(256, 4) void k_gemm(const float* __restrict__ X,
                                                 const short* __restrict__ Wpk,
                                                 float* __restrict__ xw_part) {
    __shared__ float Xs[2][GBM][32];               // 2 x 16 KB

    const int t = threadIdx.x;
    const int kpl = blockIdx.x & 7;                // K-slice (XCD-aligned via %8 dispatch)
    const int rb = blockIdx.x >> 3;                // row block 0..127
    const int block_row = rb * GBM;
    const int w = t >> 6;
    const int lane = t & 63;
    const int g = lane >> 4;                       // k-group 0..3
    const int lr = lane & 15;                      // frag row 0..15
    const int swz = lr & 7;

    // staging: lane covers row (lane>>3) of its 8-row chunk, source granule
    // pre-swizzled so LDS (linear dest) holds granule q at column q^(row&7)
    const int rsub = lane >> 3;                    // 0..7, == row&7 of dest row
    const int qsrc = (lane & 7) ^ rsub;
    const float* gl = X + (size_t)(block_row + w * 32 + rsub) * N_FEAT
                        + (size_t)kpl * KCHUNK + qsrc * 4;

    f32x4 acc[2][4] = {};
    int cur = 0;

#define STAGE(buf, kt)                                                          \
    {                                                                           \
        _Pragma("unroll")                                                       \
        for (int i = 0; i < 4; ++i)                                             \
            __builtin_amdgcn_global_load_lds(                                   \
                (const __attribute__((address_space(1))) void*)                 \
                    (gl + (size_t)i * 8 * N_FEAT + (kt) * 32),                  \
                (__attribute__((address_space(3))) void*)&Xs[buf][w * 32 + i * 8][0], \
                16, 0, 0);                                                      \
    }

    STAGE(0, 0);
    __syncthreads();

    for (int kt = 0; kt < NSTEP; ++kt) {
        if (kt + 1 < NSTEP) STAGE(cur ^ 1, kt + 1);

        // B frags from packed global (L2-hot)
        const int kstep = kpl * NSTEP + kt;
        const short* bp = Wpk + (size_t)(kstep * 4) * 512 + lane * 8;
        bf16x8 bh[4], bl[4];
        #pragma unroll
        for (int ct = 0; ct < 4; ++ct) {
            bh[ct] = *(const bf16x8*)(bp + ct * 512);
            bl[ct] = *(const bf16x8*)(bp + ct * 512 + 1048576);
        }

        // A frags: row w*32 + rt*16 + lr, k = g*8..g*8+7 (2 swizzled granules)
        const int q0 = ((2 * g) ^ swz) * 4;
        const int q1 = ((2 * g + 1) ^ swz) * 4;
        const int r0 = w * 32 + lr;
        float4 x0 = *(const float4*)&Xs[cur][r0][q0];
        float4 x1 = *(const float4*)&Xs[cur][r0][q1];
        float4 x2 = *(const float4*)&Xs[cur][r0 + 16][q0];
        float4 x3 = *(const float4*)&Xs[cur][r0 + 16][q1];
        bf16x8 ah[2], al[2];
        split8(x0, x1, ah[0], al[0]);
        split8(x2, x3, ah[1], al[1]);

        #pragma unroll
        for (int rt = 0; rt < 2; ++rt) {
            #pragma unroll
            for (int ct = 0; ct < 4; ++ct) {
                acc[rt][ct] = __builtin_amdgcn_mfma_f32_16x16x32_bf16(ah[rt], bh[ct], acc[rt][ct], 0, 0, 0);
                acc[rt][ct] = __builtin_amdgcn_mfma_f32_16x16x32_bf16(ah[rt], bl[ct], acc[rt][ct], 0, 0, 0);
                acc[rt][ct] = __builtin_amdgcn_mfma_f32_16x16x32_bf16(al[rt], bh[ct], acc[rt][ct], 0, 0, 0);
            }
        }
        __syncthreads();   // drains vmcnt (stage done) + lgkmcnt; one barrier/step
        cur ^= 1;
    }
#undef STAGE

    // epilogue: C/D layout col = lane&15, row = (lane>>4)*4 + reg (m89-verified)
    float* part = xw_part + (size_t)kpl * (N_NODES * EMBED);
    #pragma unroll
    for (int rt = 0; rt < 2; ++rt)
        #pragma unroll
        for (int ct = 0; ct < 4; ++ct)
            #pragma unroll
            for (int r = 0; r < 4; ++r) {
                int row = block_row + w * 32 + rt * 16 + g * 4 + r;
                part[(size_t)row * EMBED + ct * 16 + lr] = acc[rt][ct][r];
            }
}

// xw = sum over KSPLIT partial slices (36 MB traffic, ~10 us)
__global__ void k_reduce(const float4* __restrict__ part, float4* __restrict__ xw) {
    int i = blockIdx.x * blockDim.x + threadIdx.x;   // 262144 float4s
    float4 s = part[i];
    #pragma unroll
    for (int p = 1; p < KSPLIT; ++p) {
        float4 v = part[(size_t)p * (N_NODES * EMBED / 4) + i];
        s.x += v.x; s.y += v.y; s.z += v.z; s.w += v.w;
    }
    xw[i] = s;
}

// ---------------------------------------------------------------------------
// agg[n] = dinv[n] * ( dinv[n]*xw[n] + sum_{s in CSR[n]} dinv[s]*xw[s] )
// One wave per dst node; register accumulation, no atomics.
__global__ void k_gather(const int* __restrict__ off, const int* __restrict__ srcs,
                         const float* __restrict__ xw, const float* __restrict__ dinv,
                         float* __restrict__ agg) {
    int n = blockIdx.x * 4 + (threadIdx.x >> 6);
    int lane = threadIdx.x & 63;
    float dn = dinv[n];
    float acc = xw[(size_t)n * EMBED + lane] * dn;   // self-loop (x dn at end -> dn^2)
    int i = off[n], i1 = off[n + 1];
    for (; i + 1 < i1; i += 2) {                     // 2-way unroll: parallel loads
        int s0 = srcs[i], s1 = srcs[i + 1];
        float a0 = xw[(size_t)s0 * EMBED + lane] * dinv[s0];
        float a1 = xw[(size_t)s1 * EMBED + lane] * dinv[s1];
        acc += a0 + a1;
    }
    if (i < i1) {
        int s = srcs[i];
        acc += xw[(size_t)s * EMBED + lane] * dinv[s];
    }
    agg[(size_t)n * EMBED + lane] = acc * dn;
}

// ---------------------------------------------------------------------------
// out[b] = w_lin[i0] + w_lin[i1] + b_lin + dot(emb[i0]+b_gcn, emb[i1]+b_gcn)
__global__ void k_final(const int* __restrict__ x, const float* __restrict__ agg,
                        const float* __restrict__ b_gcn, const float* __restrict__ w_lin,
                        const float* __restrict__ b_lin, float* __restrict__ out) {
    int b = blockIdx.x * (blockDim.x >> 6) + (threadIdx.x >> 6);
    int lane = threadIdx.x & 63;
    if (b >= BATCH) return;
    int i0 = x[2 * b + 0];
    int i1 = x[2 * b + 1];
    float bg = b_gcn[lane];
    float e0 = agg[(size_t)i0 * EMBED + lane] + bg;
    float e1 = agg[(size_t)i1 * EMBED + lane] + bg;
    float p = e0 * e1;
    #pragma unroll
    for (int off = 32; off > 0; off >>= 1) p += __shfl_down(p, off, 64);
    if (lane == 0) out[b] = p + w_lin[i0] + w_lin[i1] + b_lin[0];
}

// ---------------------------------------------------------------------------
extern "C" void kernel_launch(void* const* d_in, const int* in_sizes, int n_in,
                              void* d_out, int out_size, void* d_ws, size_t ws_size,
                              hipStream_t stream) {
    (void)in_sizes; (void)n_in; (void)out_size; (void)ws_size;

    const int*   x   = (const int*)d_in[0];    // [BATCH, 2]
    const float* X   = (const float*)d_in[1];  // [N_NODES, N_FEAT]
    const int*   ei  = (const int*)d_in[2];    // [2, N_EDGES]
    const float* W   = (const float*)d_in[3];  // [N_FEAT, EMBED]
    const float* bg  = (const float*)d_in[4];  // [EMBED]
    const float* wl  = (const float*)d_in[5];  // [N_NODES]
    const float* bl  = (const float*)d_in[6];  // [1]
    float* out = (float*)d_out;                // [BATCH]

    // workspace layout:
    //   0      : xw     4 MB
    //   4 MB   : Wpk    4 MB   (aliased by agg: Wpk dead before k_gather writes)
    //   8 MB   : dinv   64 KB
    //   +128 KB: off    64 KB+4
    //   +256 KB: cur    64 KB
    //   +512 KB: srcs   2 MB
    //   16 MB  : xw_part 32 MB (KSPLIT slices)
    char* ws = (char*)d_ws;
    float* xw      = (float*)(ws);
    short* Wpk     = (short*)(ws + (size_t)(4 << 20));
    float* agg     = (float*)(ws + (size_t)(4 << 20));
    float* dinv    = (float*)(ws + (size_t)(8 << 20));
    int*   off     = (int*)  (ws + (size_t)(8 << 20) + (1 << 17));
    int*   cur     = (int*)  (ws + (size_t)(8 << 20) + (1 << 18));
    int*   srcs    = (int*)  (ws + (size_t)(8 << 20) + (1 << 19));
    float* xw_part = (float*)(ws + (size_t)(16 << 20));

    k_deg_init<<<N_NODES / 256, 256, 0, stream>>>(dinv);
    k_deg_acc<<<N_EDGES / 256, 256, 0, stream>>>(ei, dinv);
    k_scan<<<1, 1024, 0, stream>>>(dinv, off, cur);       // needs raw deg
    k_dinv<<<N_NODES / 256, 256, 0, stream>>>(dinv);      // deg -> rsqrt(deg)
    k_scatter<<<N_EDGES / 256, 256, 0, stream>>>(ei, cur, srcs);

    k_wpack<<<1024, 256, 0, stream>>>(W, Wpk);
    k_gemm<<<(N_NODES / GBM) * KSPLIT, 256, 0, stream>>>(X, Wpk, xw_part);
    k_reduce<<<(N_NODES * EMBED / 4) / 256, 256, 0, stream>>>((const float4*)xw_part, (float4*)xw);

    k_gather<<<N_NODES / 4, 256, 0, stream>>>(off, srcs, xw, dinv, agg);
    k_final<<<BATCH / 4, 256, 0, stream>>>(x, agg, bg, wl, bl, out);
}